// Round 13
// baseline (142.204 us; speedup 1.0000x reference)
//
#include <hip/hip_runtime.h>

#define BATCH 256
#define SEQ   512
#define NT    64
#define PCH   12    // chunks per sequence
#define CLEN  43    // steps per chunk (12*43=516 >= 511; last chunk L=38)
#define PITCH 68    // ldsT pitch in halves (2-way bank aliasing on combine reads = free)
#define SLICE_CH 11008  // per-chunk LDS slice: max(43*64*4=11008, 64*68*2=8704)

typedef __attribute__((ext_vector_type(8)))  short bf16x8;
typedef __attribute__((ext_vector_type(16))) float f32x16;
typedef __attribute__((ext_vector_type(4)))  float f32x4;
typedef __attribute__((ext_vector_type(2)))  float f32x2;

static __device__ __forceinline__ unsigned pk_bf16(float lo, float hi) {
    // dst = lo.bf16 | (hi.bf16 << 16), truncation — single v_perm_b32
    return __builtin_amdgcn_perm(__float_as_uint(hi), __float_as_uint(lo), 0x07060302u);
}
static __device__ __forceinline__ short bf16_trunc(float v) {
    return (short)(__float_as_uint(v) >> 16);
}

// ---------------------------------------------------------------------------
// Whole-batch fused CRF kernel at R1's winning occupancy. Grid = BATCH WGs x
// 768 threads (12 full-width waves = 12 chunks). Wave wv = chunk c, full
// 64-column chain (16 MFMA/step, nt-sequential, setprio — R1 body verbatim).
// 12 waves/CU = 3 waves/SIMD: the regime where the chunk phase measured
// 70-73 µs (R1/R6) vs 80 µs at 2 waves/SIMD (R12). MfmaUtil(35%)+VALU(27%)
// at 2 w/SIMD says issue slots are the currency; the 3rd wave fills them.
// launch_bounds(768,3) -> 170-reg budget, proven spill-free for this body
// (R1/R6: VGPR 68-72). LDS 12 x 11008 = 132 KB -> 1 WG/CU. Combine in-WG.
// ---------------------------------------------------------------------------
__global__ __launch_bounds__(768, 3) void crf_fused(
    const float* __restrict__ emissions,   // (B,S,T)
    const int*   __restrict__ tags,
    const int*   __restrict__ mask,
    const float* __restrict__ start_tr,
    const float* __restrict__ end_tr,
    const float* __restrict__ trans,       // (T,T)
    float* __restrict__ ws_head,           // [0]=sum f32, [1]=cnt u32 (memset 0)
    float* __restrict__ out)
{
    __shared__ __align__(16) unsigned char smem[PCH * SLICE_CH];  // 132 KB
    __shared__ __align__(16) float r_lds[NT];
    __shared__ float score_lds;

    const int tid  = threadIdx.x;
    const int lane = tid & 63;
    const int wv   = tid >> 6;
    const int b    = blockIdx.x;
    const int c    = wv;               // one wave = one whole chunk

    unsigned char* slice = smem + c * SLICE_CH;
    float (*w_lds)[NT]   = (float (*)[NT])slice;
    unsigned short* ldsT = (unsigned short*)slice;

    const int h  = lane >> 5;
    const int ml = lane & 31;

    const int s0 = c * CLEN;
    int L = (SEQ - 1) - s0; if (L > CLEN) L = CLEN;

    const float* em_b = emissions + (size_t)b * SEQ * NT;

    // ---- staging: w = exp(em), wave-private slice (R1 pattern) ----
    {
        const float4* src = (const float4*)(em_b + (size_t)(s0 + 1) * NT);
        float4*       dst = (float4*)slice;
        const int total4 = L * (NT / 4);
        for (int i = lane; i < total4; i += 64) {
            float4 v = src[i];
            v.x = __expf(v.x); v.y = __expf(v.y);
            v.z = __expf(v.z); v.w = __expf(v.w);
            dst[i] = v;
        }
    }

    // Permuted A: Af[mt][kk] slot (h,j) = Es[mt*32+ml][r], Es = E^T * 2^-7,
    // r = 32*(kk>>1) + 16*(kk&1) + (j&3) + 8*(j>>2) + 4h
    bf16x8 Af[2][4];
#pragma unroll
    for (int mt = 0; mt < 2; ++mt) {
        int m = mt * 32 + ml;
#pragma unroll
        for (int kk = 0; kk < 4; ++kk) {
            bf16x8 f;
#pragma unroll
            for (int j = 0; j < 8; ++j) {
                int r = 32 * (kk >> 1) + 16 * (kk & 1) + (j & 3) + 8 * (j >> 2) + 4 * h;
                f[j] = bf16_trunc(__expf(trans[r * NT + m]) * 0.0078125f);
            }
            Af[mt][kk] = f;
        }
    }

    // B := identity (permuted-B register convention), both column halves
    union BU { unsigned u[4]; bf16x8 v; };
    BU Bv[4][2];
#pragma unroll
    for (int kk = 0; kk < 4; ++kk)
#pragma unroll
        for (int nt = 0; nt < 2; ++nt) {
            int n = nt * 32 + ml;
#pragma unroll
            for (int d = 0; d < 4; ++d) {
                int j0 = 2 * d;
                int r0 = 32 * (kk >> 1) + 16 * (kk & 1) + (j0 & 3) + 8 * (j0 >> 2) + 4 * h;
                unsigned lo = (r0     == n) ? 0x3f80u : 0u;
                unsigned hi = (r0 + 1 == n) ? 0x3f80u : 0u;
                Bv[kk][nt].u[d] = lo | (hi << 16);
            }
        }

    __threadfence_block();  // own w writes ordered before own loop reads

    const f32x16 zf = {};   // persistent zero C operand

    for (int s = 0; s < L; ++s) {
        // w quads for this step (broadcast reads, issued before MFMAs)
        const float* wrow = w_lds[s];
        f32x4 wq[4][2];
#pragma unroll
        for (int kk = 0; kk < 4; ++kk) {
            int base = 32 * (kk >> 1) + 16 * (kk & 1) + 4 * h;
            wq[kk][0] = *(const f32x4*)(wrow + base);
            wq[kk][1] = *(const f32x4*)(wrow + base + 8);
        }

        // nt slices independent: process sequentially to halve live accs
#pragma unroll
        for (int nt = 0; nt < 2; ++nt) {
            __builtin_amdgcn_s_setprio(1);
            // layered K: consecutive MFMAs independent (dep distance 2)
            f32x16 a0 = __builtin_amdgcn_mfma_f32_32x32x16_bf16(Af[0][0], Bv[0][nt].v, zf, 0, 0, 0);
            f32x16 a1 = __builtin_amdgcn_mfma_f32_32x32x16_bf16(Af[1][0], Bv[0][nt].v, zf, 0, 0, 0);
#pragma unroll
            for (int kk = 1; kk < 4; ++kk) {
                a0 = __builtin_amdgcn_mfma_f32_32x32x16_bf16(Af[0][kk], Bv[kk][nt].v, a0, 0, 0, 0);
                a1 = __builtin_amdgcn_mfma_f32_32x32x16_bf16(Af[1][kk], Bv[kk][nt].v, a1, 0, 0, 0);
            }
            __builtin_amdgcn_s_setprio(0);

            // Rebuild B[:,nt] from row-scaled C: value (kk,h,j) = w[r]*C[r][n]
#pragma unroll
            for (int kk = 0; kk < 4; ++kk) {
                const int qo = 8 * (kk & 1);
                const f32x4 wa = wq[kk][0], wb = wq[kk][1];
#pragma unroll
                for (int d = 0; d < 4; ++d) {
                    const int j0 = 2 * d;
                    float w0 = (d < 2) ? wa[j0]     : wb[j0 - 4];
                    float w1 = (d < 2) ? wa[j0 + 1] : wb[j0 - 3];
                    f32x2 av, wvv;
                    if (kk < 2) { av[0] = a0[qo + j0]; av[1] = a0[qo + j0 + 1]; }
                    else        { av[0] = a1[qo + j0]; av[1] = a1[qo + j0 + 1]; }
                    wvv[0] = w0; wvv[1] = w1;
                    f32x2 p = av * wvv;          // v_pk_mul_f32
                    Bv[kk][nt].u[d] = pk_bf16(p[0], p[1]);
                }
            }
        }
    }

    // Transpose into own LDS slice (ldsT overlays own w): ldsT[n*PITCH+k]=M[k][n]
    __threadfence_block();
#pragma unroll
    for (int kk = 0; kk < 4; ++kk)
#pragma unroll
        for (int nt = 0; nt < 2; ++nt) {
            int n = nt * 32 + ml;
#pragma unroll
            for (int d = 0; d < 4; ++d) {
                int j0 = 2 * d;
                int r0 = 32 * (kk >> 1) + 16 * (kk & 1) + (j0 & 3) + 8 * (j0 >> 2) + 4 * h;
                *(unsigned*)&ldsT[n * PITCH + r0] = Bv[kk][nt].u[d];
            }
        }

    __syncthreads();    // all 12 chunk matrices materialized in LDS

    // ------------------- combine (in-WG, LDS-resident) -------------------
    const int j = lane;
    float denom = 0.f;

    if (wv == 1) {
        // ---------------- numerator (gold-path score) ----------------
        const int* tg_b = tags + b * SEQ;
        const int* mk_b = mask + b * SEQ;
        float part = 0.f;
        int mcount = 0;
        for (int s = j; s < SEQ; s += 64) {
            int m = mk_b[s];
            mcount += m;
            int t = tg_b[s];
            if (s == 0) {
                part += start_tr[t] + em_b[t];
            } else {
                int tp = tg_b[s - 1];
                float v = trans[tp * NT + t] + em_b[s * NT + t];
                part += m ? v : 0.f;
            }
        }
#pragma unroll
        for (int d = 32; d; d >>= 1) {
            part   += __shfl_xor(part, d);
            mcount += __shfl_xor(mcount, d);
        }
        if (j == 0) score_lds = part + end_tr[tg_b[mcount - 1]];
    } else if (wv == 0) {
        // ------------- chain: r^T <- r^T M_c, c = PCH-1..0, from LDS -------------
        float r = __expf(end_tr[j]);
        r_lds[j] = r;
        __threadfence_block();
        int X = 0;

        for (int cc = PCH - 1; cc >= 0; --cc) {
            // row j of M_cc^T = ldsT_cc[j*PITCH + k], k = 0..63 (bf16)
            const unsigned short* Trow = (const unsigned short*)(smem + cc * SLICE_CH) + j * PITCH;
            float a0 = 0.f, a1 = 0.f, a2 = 0.f, a3 = 0.f;
#pragma unroll
            for (int u = 0; u < 8; ++u) {
                uint2 q0 = *(const uint2*)(Trow + u * 8);       // halves 0..3 (8B aligned)
                uint2 q1 = *(const uint2*)(Trow + u * 8 + 4);   // halves 4..7
                f32x4 ra = *(const f32x4*)&r_lds[u * 8];
                f32x4 rb = *(const f32x4*)&r_lds[u * 8 + 4];
                a0 = fmaf(ra[0], __uint_as_float(q0.x << 16),         a0);
                a1 = fmaf(ra[1], __uint_as_float(q0.x & 0xffff0000u), a1);
                a2 = fmaf(ra[2], __uint_as_float(q0.y << 16),         a2);
                a3 = fmaf(ra[3], __uint_as_float(q0.y & 0xffff0000u), a3);
                a0 = fmaf(rb[0], __uint_as_float(q1.x << 16),         a0);
                a1 = fmaf(rb[1], __uint_as_float(q1.x & 0xffff0000u), a1);
                a2 = fmaf(rb[2], __uint_as_float(q1.y << 16),         a2);
                a3 = fmaf(rb[3], __uint_as_float(q1.y & 0xffff0000u), a3);
            }
            float rn = (a0 + a1) + (a2 + a3);
            unsigned eb = (__builtin_amdgcn_readfirstlane((int)__float_as_uint(rn)) >> 23) & 0xffu;
            r = rn * __uint_as_float((254u - eb) << 23);   // * 2^(127-eb)
            X += (int)eb - 127;
            r_lds[j] = r;
            __threadfence_block();
        }

        float u0 = __expf(start_tr[j] + em_b[j]);
        float v = r * u0;
#pragma unroll
        for (int d = 32; d; d >>= 1) v += __shfl_xor(v, d);
        denom = __logf(v) + (float)(X + 7 * (SEQ - 1)) * 0.6931471805599453f;
    }

    __syncthreads();  // score_lds ready

    if (wv == 0 && j == 0) {
        float llh = denom - score_lds;
        atomicAdd(&ws_head[0], llh * (1.0f / BATCH));
        __threadfence();
        unsigned old = atomicAdd((unsigned*)ws_head + 1, 1u);
        if (old == BATCH - 1) {
            __threadfence();
            out[0] = atomicAdd(&ws_head[0], 0.0f);  // coherent read of final sum
        }
    }
}

extern "C" void kernel_launch(void* const* d_in, const int* in_sizes, int n_in,
                              void* d_out, int out_size, void* d_ws, size_t ws_size,
                              hipStream_t stream) {
    const float* emissions = (const float*)d_in[0];
    const int*   tags      = (const int*)d_in[1];
    const int*   mask      = (const int*)d_in[2];
    const float* start_tr  = (const float*)d_in[3];
    const float* end_tr    = (const float*)d_in[4];
    const float* trans     = (const float*)d_in[5];

    float* ws_head = (float*)d_ws;   // [0]=sum, [1]=cnt

    // zero sum/cnt (graph-capturable, stream-ordered before the kernel)
    hipMemsetAsync(d_ws, 0, 256, stream);

    // One WG per batch: 12 full-width waves = 12 chunks; combine in-WG.
    crf_fused<<<dim3(BATCH), 768, 0, stream>>>(emissions, tags, mask,
                                               start_tr, end_tr, trans,
                                               ws_head, (float*)d_out);
}

// Round 14
// 141.272 us; speedup vs baseline: 1.0066x; 1.0066x over previous
//
#include <hip/hip_runtime.h>

#define BATCH 256
#define SEQ   512
#define NT    64
#define PCH   12    // chunks per sequence
#define CLEN  43    // steps per chunk (12*43=516 >= 511; last chunk L=38)
#define PITCH 68    // ldsT pitch in halves (2-way bank aliasing on combine reads = free)
#define SLICE_CH 11008  // per-chunk LDS slice: max(43*64*4=11008, 64*68*2=8704)

typedef __attribute__((ext_vector_type(8)))  short bf16x8;
typedef __attribute__((ext_vector_type(16))) float f32x16;
typedef __attribute__((ext_vector_type(4)))  float f32x4;
typedef __attribute__((ext_vector_type(2)))  float f32x2;

static __device__ __forceinline__ unsigned pk_bf16(float lo, float hi) {
    // dst = lo.bf16 | (hi.bf16 << 16), truncation — single v_perm_b32
    return __builtin_amdgcn_perm(__float_as_uint(hi), __float_as_uint(lo), 0x07060302u);
}
static __device__ __forceinline__ short bf16_trunc(float v) {
    return (short)(__float_as_uint(v) >> 16);
}

// ---------------------------------------------------------------------------
// Whole-batch fused CRF kernel (R13) + wq register double-buffer (R11's
// theory, retried at the budget where it fits). Grid = BATCH WGs x 768
// threads (12 full-width waves = 12 chunks). launch_bounds(768,3) ->
// 170-reg budget; R13 measured VGPR 76, so the +32-reg second wq buffer
// has ~90 regs of headroom (R11's spill was the half-width kernel's
// 128-reg budget). Step s's repack consumes a wq buffer issued before
// step s-1's MFMA block -> full-step (~4000cy) LDS latency cover,
// targeting the ~16x stall ratio that survives 3 waves/SIMD.
// ---------------------------------------------------------------------------
__global__ __launch_bounds__(768, 3) void crf_fused(
    const float* __restrict__ emissions,   // (B,S,T)
    const int*   __restrict__ tags,
    const int*   __restrict__ mask,
    const float* __restrict__ start_tr,
    const float* __restrict__ end_tr,
    const float* __restrict__ trans,       // (T,T)
    float* __restrict__ ws_head,           // [0]=sum f32, [1]=cnt u32 (memset 0)
    float* __restrict__ out)
{
    __shared__ __align__(16) unsigned char smem[PCH * SLICE_CH];  // 132 KB
    __shared__ __align__(16) float r_lds[NT];
    __shared__ float score_lds;

    const int tid  = threadIdx.x;
    const int lane = tid & 63;
    const int wv   = tid >> 6;
    const int b    = blockIdx.x;
    const int c    = wv;               // one wave = one whole chunk

    unsigned char* slice = smem + c * SLICE_CH;
    float (*w_lds)[NT]   = (float (*)[NT])slice;
    unsigned short* ldsT = (unsigned short*)slice;

    const int h  = lane >> 5;
    const int ml = lane & 31;

    const int s0 = c * CLEN;
    int L = (SEQ - 1) - s0; if (L > CLEN) L = CLEN;

    const float* em_b = emissions + (size_t)b * SEQ * NT;

    // ---- staging: w = exp(em), wave-private slice ----
    {
        const float4* src = (const float4*)(em_b + (size_t)(s0 + 1) * NT);
        float4*       dst = (float4*)slice;
        const int total4 = L * (NT / 4);
        for (int i = lane; i < total4; i += 64) {
            float4 v = src[i];
            v.x = __expf(v.x); v.y = __expf(v.y);
            v.z = __expf(v.z); v.w = __expf(v.w);
            dst[i] = v;
        }
    }

    // Permuted A: Af[mt][kk] slot (h,j) = Es[mt*32+ml][r], Es = E^T * 2^-7,
    // r = 32*(kk>>1) + 16*(kk&1) + (j&3) + 8*(j>>2) + 4h
    bf16x8 Af[2][4];
#pragma unroll
    for (int mt = 0; mt < 2; ++mt) {
        int m = mt * 32 + ml;
#pragma unroll
        for (int kk = 0; kk < 4; ++kk) {
            bf16x8 f;
#pragma unroll
            for (int j = 0; j < 8; ++j) {
                int r = 32 * (kk >> 1) + 16 * (kk & 1) + (j & 3) + 8 * (j >> 2) + 4 * h;
                f[j] = bf16_trunc(__expf(trans[r * NT + m]) * 0.0078125f);
            }
            Af[mt][kk] = f;
        }
    }

    // B := identity (permuted-B register convention), both column halves
    union BU { unsigned u[4]; bf16x8 v; };
    BU Bv[4][2];
#pragma unroll
    for (int kk = 0; kk < 4; ++kk)
#pragma unroll
        for (int nt = 0; nt < 2; ++nt) {
            int n = nt * 32 + ml;
#pragma unroll
            for (int d = 0; d < 4; ++d) {
                int j0 = 2 * d;
                int r0 = 32 * (kk >> 1) + 16 * (kk & 1) + (j0 & 3) + 8 * (j0 >> 2) + 4 * h;
                unsigned lo = (r0     == n) ? 0x3f80u : 0u;
                unsigned hi = (r0 + 1 == n) ? 0x3f80u : 0u;
                Bv[kk][nt].u[d] = lo | (hi << 16);
            }
        }

    __threadfence_block();  // own w writes ordered before own loop reads

    const f32x16 zf = {};   // persistent zero C operand

    // 8x ds_read_b128 of this step's broadcast w quads
#define LOAD_WQ(WQ, S)                                                         \
    {                                                                          \
        const float* wrow_ = w_lds[(S)];                                       \
        _Pragma("unroll")                                                      \
        for (int kk = 0; kk < 4; ++kk) {                                       \
            int base_ = 32 * (kk >> 1) + 16 * (kk & 1) + 4 * h;                \
            WQ[kk][0] = *(const f32x4*)(wrow_ + base_);                        \
            WQ[kk][1] = *(const f32x4*)(wrow_ + base_ + 8);                    \
        }                                                                      \
    }

    // one full-width chain step (R13 body verbatim), repack weights from WQ
#define STEP_BODY(WQ)                                                          \
    {                                                                          \
        _Pragma("unroll")                                                      \
        for (int nt = 0; nt < 2; ++nt) {                                       \
            __builtin_amdgcn_s_setprio(1);                                     \
            f32x16 a0 = __builtin_amdgcn_mfma_f32_32x32x16_bf16(Af[0][0], Bv[0][nt].v, zf, 0, 0, 0); \
            f32x16 a1 = __builtin_amdgcn_mfma_f32_32x32x16_bf16(Af[1][0], Bv[0][nt].v, zf, 0, 0, 0); \
            _Pragma("unroll")                                                  \
            for (int kk = 1; kk < 4; ++kk) {                                   \
                a0 = __builtin_amdgcn_mfma_f32_32x32x16_bf16(Af[0][kk], Bv[kk][nt].v, a0, 0, 0, 0); \
                a1 = __builtin_amdgcn_mfma_f32_32x32x16_bf16(Af[1][kk], Bv[kk][nt].v, a1, 0, 0, 0); \
            }                                                                  \
            __builtin_amdgcn_s_setprio(0);                                     \
            _Pragma("unroll")                                                  \
            for (int kk = 0; kk < 4; ++kk) {                                   \
                const int qo = 8 * (kk & 1);                                   \
                const f32x4 wa = WQ[kk][0], wb = WQ[kk][1];                    \
                _Pragma("unroll")                                              \
                for (int d = 0; d < 4; ++d) {                                  \
                    const int j0 = 2 * d;                                      \
                    float w0 = (d < 2) ? wa[j0]     : wb[j0 - 4];              \
                    float w1 = (d < 2) ? wa[j0 + 1] : wb[j0 - 3];              \
                    f32x2 av, wvv;                                             \
                    if (kk < 2) { av[0] = a0[qo + j0]; av[1] = a0[qo + j0 + 1]; } \
                    else        { av[0] = a1[qo + j0]; av[1] = a1[qo + j0 + 1]; } \
                    wvv[0] = w0; wvv[1] = w1;                                  \
                    f32x2 p = av * wvv;                                        \
                    Bv[kk][nt].u[d] = pk_bf16(p[0], p[1]);                     \
                }                                                              \
            }                                                                  \
        }                                                                      \
    }

    // explicit 2-step pipeline: repack(s) uses a buffer issued before
    // step s-1's MFMA block (full-step LDS-latency cover; named buffers)
    f32x4 wqA[4][2], wqB[4][2];
    LOAD_WQ(wqA, 0)
    for (int s = 0; s < L; s += 2) {
        const bool has1 = (s + 1 < L);
        if (has1) LOAD_WQ(wqB, s + 1)
        STEP_BODY(wqA)
        if (has1) {
            if (s + 2 < L) LOAD_WQ(wqA, s + 2)
            STEP_BODY(wqB)
        }
    }
#undef LOAD_WQ
#undef STEP_BODY

    // Transpose into own LDS slice (ldsT overlays own w): ldsT[n*PITCH+k]=M[k][n]
    __threadfence_block();
#pragma unroll
    for (int kk = 0; kk < 4; ++kk)
#pragma unroll
        for (int nt = 0; nt < 2; ++nt) {
            int n = nt * 32 + ml;
#pragma unroll
            for (int d = 0; d < 4; ++d) {
                int j0 = 2 * d;
                int r0 = 32 * (kk >> 1) + 16 * (kk & 1) + (j0 & 3) + 8 * (j0 >> 2) + 4 * h;
                *(unsigned*)&ldsT[n * PITCH + r0] = Bv[kk][nt].u[d];
            }
        }

    __syncthreads();    // all 12 chunk matrices materialized in LDS

    // ------------------- combine (in-WG, LDS-resident) -------------------
    const int j = lane;
    float denom = 0.f;

    if (wv == 1) {
        // ---------------- numerator (gold-path score) ----------------
        const int* tg_b = tags + b * SEQ;
        const int* mk_b = mask + b * SEQ;
        float part = 0.f;
        int mcount = 0;
        for (int s = j; s < SEQ; s += 64) {
            int m = mk_b[s];
            mcount += m;
            int t = tg_b[s];
            if (s == 0) {
                part += start_tr[t] + em_b[t];
            } else {
                int tp = tg_b[s - 1];
                float v = trans[tp * NT + t] + em_b[s * NT + t];
                part += m ? v : 0.f;
            }
        }
#pragma unroll
        for (int d = 32; d; d >>= 1) {
            part   += __shfl_xor(part, d);
            mcount += __shfl_xor(mcount, d);
        }
        if (j == 0) score_lds = part + end_tr[tg_b[mcount - 1]];
    } else if (wv == 0) {
        // ------------- chain: r^T <- r^T M_c, c = PCH-1..0, from LDS -------------
        float r = __expf(end_tr[j]);
        r_lds[j] = r;
        __threadfence_block();
        int X = 0;

        for (int cc = PCH - 1; cc >= 0; --cc) {
            // row j of M_cc^T = ldsT_cc[j*PITCH + k], k = 0..63 (bf16)
            const unsigned short* Trow = (const unsigned short*)(smem + cc * SLICE_CH) + j * PITCH;
            float a0 = 0.f, a1 = 0.f, a2 = 0.f, a3 = 0.f;
#pragma unroll
            for (int u = 0; u < 8; ++u) {
                uint2 q0 = *(const uint2*)(Trow + u * 8);       // halves 0..3 (8B aligned)
                uint2 q1 = *(const uint2*)(Trow + u * 8 + 4);   // halves 4..7
                f32x4 ra = *(const f32x4*)&r_lds[u * 8];
                f32x4 rb = *(const f32x4*)&r_lds[u * 8 + 4];
                a0 = fmaf(ra[0], __uint_as_float(q0.x << 16),         a0);
                a1 = fmaf(ra[1], __uint_as_float(q0.x & 0xffff0000u), a1);
                a2 = fmaf(ra[2], __uint_as_float(q0.y << 16),         a2);
                a3 = fmaf(ra[3], __uint_as_float(q0.y & 0xffff0000u), a3);
                a0 = fmaf(rb[0], __uint_as_float(q1.x << 16),         a0);
                a1 = fmaf(rb[1], __uint_as_float(q1.x & 0xffff0000u), a1);
                a2 = fmaf(rb[2], __uint_as_float(q1.y << 16),         a2);
                a3 = fmaf(rb[3], __uint_as_float(q1.y & 0xffff0000u), a3);
            }
            float rn = (a0 + a1) + (a2 + a3);
            unsigned eb = (__builtin_amdgcn_readfirstlane((int)__float_as_uint(rn)) >> 23) & 0xffu;
            r = rn * __uint_as_float((254u - eb) << 23);   // * 2^(127-eb)
            X += (int)eb - 127;
            r_lds[j] = r;
            __threadfence_block();
        }

        float u0 = __expf(start_tr[j] + em_b[j]);
        float v = r * u0;
#pragma unroll
        for (int d = 32; d; d >>= 1) v += __shfl_xor(v, d);
        denom = __logf(v) + (float)(X + 7 * (SEQ - 1)) * 0.6931471805599453f;
    }

    __syncthreads();  // score_lds ready

    if (wv == 0 && j == 0) {
        float llh = denom - score_lds;
        atomicAdd(&ws_head[0], llh * (1.0f / BATCH));
        __threadfence();
        unsigned old = atomicAdd((unsigned*)ws_head + 1, 1u);
        if (old == BATCH - 1) {
            __threadfence();
            out[0] = atomicAdd(&ws_head[0], 0.0f);  // coherent read of final sum
        }
    }
}

extern "C" void kernel_launch(void* const* d_in, const int* in_sizes, int n_in,
                              void* d_out, int out_size, void* d_ws, size_t ws_size,
                              hipStream_t stream) {
    const float* emissions = (const float*)d_in[0];
    const int*   tags      = (const int*)d_in[1];
    const int*   mask      = (const int*)d_in[2];
    const float* start_tr  = (const float*)d_in[3];
    const float* end_tr    = (const float*)d_in[4];
    const float* trans     = (const float*)d_in[5];

    float* ws_head = (float*)d_ws;   // [0]=sum, [1]=cnt

    // zero sum/cnt (graph-capturable, stream-ordered before the kernel)
    hipMemsetAsync(d_ws, 0, 256, stream);

    // One WG per batch: 12 full-width waves = 12 chunks; combine in-WG.
    crf_fused<<<dim3(BATCH), 768, 0, stream>>>(emissions, tags, mask,
                                               start_tr, end_tr, trans,
                                               ws_head, (float*)d_out);
}